// Round 8
// baseline (636.775 us; speedup 1.0000x reference)
//
#include <hip/hip_runtime.h>
#include <cstddef>

#define NN   50000
#define KNB  32

typedef _Float16 h2    __attribute__((ext_vector_type(2)));
typedef _Float16 h4    __attribute__((ext_vector_type(4)));
typedef _Float16 half8 __attribute__((ext_vector_type(8)));
typedef float    f4    __attribute__((ext_vector_type(4)));

// ---------------- prep: W1^T and W2^T as fp16 [N][K] ----------------------
__global__ __launch_bounds__(256) void prep(const float* __restrict__ W1,
                                            const float* __restrict__ W2,
                                            _Float16* __restrict__ w1t,
                                            _Float16* __restrict__ w2t) {
  const int id = blockIdx.x * 256 + threadIdx.x;
  if (id < 128 * 512) {                     // w1t[n][k] = W1[k][n]
    const int n = id >> 9, k = id & 511;
    w1t[id] = (_Float16)W1[k * 128 + n];
  } else {
    const int id2 = id - 128 * 512;
    if (id2 < 64 * 128) {                   // w2t[n][k] = W2[k][n]
      const int n = id2 >> 7, k = id2 & 127;
      w2t[id2] = (_Float16)W2[k * 64 + n];
    }
  }
}

// ---------------- GEMM1: H1[M,128] = A[M,512]fp32 @ W1 + b1, fp16 out -----
// R11 structure (lane-consecutive staging, BM=64, BK=64). Unchanged.
__global__ __launch_bounds__(256) void gemm1_mfma(
    const float* __restrict__ A, const _Float16* __restrict__ Bt,
    const float* __restrict__ bias, _Float16* __restrict__ C, int M) {
  constexpr int K = 512, BM = 64, BK = 64;
  __shared__ _Float16 Ah[BM][72];     // 9 KB, 144B stride
  __shared__ _Float16 Bh[128][72];    // 18 KB
  const int tid  = threadIdx.x;
  const int wave = tid >> 6;
  const int lane = tid & 63;
  const int mr   = lane & 15;
  const int kg   = lane >> 4;
  const int m0   = blockIdx.x * BM;

  const int ar = tid >> 4;            // 0..15 (+ c*16)
  const int ac = (tid & 15) * 4;      // fp32 col within BK
  const int br = tid >> 3;            // 0..31 (+ c*32)
  const int bc = (tid & 7) * 8;       // fp16 col within BK

  f4 acc[8] = {};

  for (int k0 = 0; k0 < K; k0 += BK) {
    #pragma unroll
    for (int c = 0; c < 4; ++c) {
      const int arow = c * 16 + ar;
      int aRow = m0 + arow;
      if (aRow >= M) aRow = M - 1;    // clamp; garbage rows dropped at store
      const f4 t = *(const f4*)(A + (size_t)aRow * K + k0 + ac);
      h4 hv = {(_Float16)t[0], (_Float16)t[1], (_Float16)t[2], (_Float16)t[3]};
      *(h4*)&Ah[arow][ac] = hv;
      const int brow = c * 32 + br;
      *(half8*)&Bh[brow][bc] =
          *(const half8*)(Bt + (size_t)brow * K + k0 + bc);
    }
    __syncthreads();

    #pragma unroll
    for (int kk = 0; kk < 2; ++kk) {
      const half8 af = *(const half8*)&Ah[wave * 16 + mr][kk * 32 + kg * 8];
      #pragma unroll
      for (int nt = 0; nt < 8; ++nt) {
        const half8 bf = *(const half8*)&Bh[nt * 16 + mr][kk * 32 + kg * 8];
        acc[nt] = __builtin_amdgcn_mfma_f32_16x16x32_f16(af, bf, acc[nt], 0, 0, 0);
      }
    }
    __syncthreads();
  }

  #pragma unroll
  for (int nt = 0; nt < 8; ++nt) {
    const int col = nt * 16 + mr;
    const float bv = bias[col];
    #pragma unroll
    for (int r = 0; r < 4; ++r) {
      const int row = m0 + wave * 16 + kg * 4 + r;
      if (row < M)
        C[(size_t)row * 128 + col] = (_Float16)(acc[nt][r] + bv);
    }
  }
}

// ---------------- GEMM2: H2[M,64] = A[M,128]fp16 @ W2 + b2, fp16 out ------
// R11 structure. Unchanged.
__global__ __launch_bounds__(256) void gemm2_mfma(
    const _Float16* __restrict__ A, const _Float16* __restrict__ Bt,
    const float* __restrict__ bias, _Float16* __restrict__ C, int M) {
  constexpr int K = 128, BM = 64, BK = 64;
  __shared__ _Float16 Ah[BM][72];     // 9 KB
  __shared__ _Float16 Bh[64][72];     // 9 KB
  const int tid  = threadIdx.x;
  const int wave = tid >> 6;
  const int lane = tid & 63;
  const int mr   = lane & 15;
  const int kg   = lane >> 4;
  const int m0   = blockIdx.x * BM;

  const int sr = tid >> 3;            // 0..31 (+ c*32)
  const int sc = (tid & 7) * 8;

  f4 acc[4] = {};

  #pragma unroll
  for (int k0 = 0; k0 < K; k0 += BK) {
    #pragma unroll
    for (int c = 0; c < 2; ++c) {
      const int srow = c * 32 + sr;
      int aRow = m0 + srow;
      if (aRow >= M) aRow = M - 1;
      *(half8*)&Ah[srow][sc] = *(const half8*)(A + (size_t)aRow * K + k0 + sc);
      *(half8*)&Bh[srow][sc] = *(const half8*)(Bt + (size_t)srow * K + k0 + sc);
    }
    __syncthreads();

    #pragma unroll
    for (int kk = 0; kk < 2; ++kk) {
      const half8 af = *(const half8*)&Ah[wave * 16 + mr][kk * 32 + kg * 8];
      #pragma unroll
      for (int nt = 0; nt < 4; ++nt) {
        const half8 bf = *(const half8*)&Bh[nt * 16 + mr][kk * 32 + kg * 8];
        acc[nt] = __builtin_amdgcn_mfma_f32_16x16x32_f16(af, bf, acc[nt], 0, 0, 0);
      }
    }
    __syncthreads();
  }

  #pragma unroll
  for (int nt = 0; nt < 4; ++nt) {
    const int col = nt * 16 + mr;
    const float bv = bias[col];
    #pragma unroll
    for (int r = 0; r < 4; ++r) {
      const int row = m0 + wave * 16 + kg * 4 + r;
      if (row < M)
        C[(size_t)row * 64 + col] = (_Float16)(acc[nt][r] + bv);
    }
  }
}

// ---------------- median machinery ----------------------------------------
// R16: pair-split cooperative median. R14/R15 established the cost is AGPR
// round-trips from >64-reg peak liveness at the allocator's 8-wave target.
// New structure: one (node,col2) item = lane pair (L, L+32). Each lane loads
// and sorts only 16 values (peak live ~45 regs < 64 -> no AGPR parking at
// full occupancy). Merge-select streams via __shfl_xor(.,32): h=1 sends
// b[14-i] (free index renaming), both halves fold min(m, max(own,recv)).
// Identical value network as R9 -> bit-identical output.
__device__ __forceinline__ void ceh(h2& a, h2& b) {
  h2 lo = __builtin_elementwise_min(a, b);
  h2 hi = __builtin_elementwise_max(a, b);
  a = lo;
  b = hi;
}

// Batcher odd-even mergesort over a 16-array (63 comparators).
__device__ __forceinline__ void sort16h(h2 (&v)[16]) {
  #pragma unroll
  for (int p = 1; p < 16; p <<= 1) {
    #pragma unroll
    for (int k = p; k >= 1; k >>= 1) {
      #pragma unroll
      for (int j = k & (p - 1); j + k < 16; j += 2 * k) {
        #pragma unroll
        for (int i = 0; i < k; ++i) {
          if (i + j + k < 16) {
            if ((i + j) / (2 * p) == (i + j + k) / (2 * p)) {
              ceh(v[i + j], v[i + j + k]);
            }
          }
        }
      }
    }
  }
}

__device__ __forceinline__ h2 shx32(h2 x) {
  int xi = __builtin_bit_cast(int, x);
  int r = __shfl_xor(xi, 32, 64);
  return __builtin_bit_cast(h2, r);
}

// Cooperative lower-median of 32: lane holds sorted half v[16]; h=0 owns
// a (nbrs 0-15), h=1 owns b (nbrs 16-31). Both converged through shfls.
// med = min(a[15], b[15], max(a[i], b[14-i]) for i=0..14)  [R9-verified].
__device__ __forceinline__ h2 median32_pair(h2 (&v)[16], int h) {
  sort16h(v);
  h2 m;
  #pragma unroll
  for (int i = 0; i < 15; ++i) {
    const h2 own = h ? v[14 - i] : v[i];
    const h2 rec = shx32(own);
    const h2 mx = __builtin_elementwise_max(own, rec);
    m = (i == 0) ? mx : __builtin_elementwise_min(m, mx);
    if (i == 4 || i == 9)               // cap shfl hoisting / liveness
      __builtin_amdgcn_sched_barrier(0);
  }
  const h2 own15 = v[15];
  const h2 rec15 = shx32(own15);
  return __builtin_elementwise_min(
      m, __builtin_elementwise_min(own15, rec15));
}

// Median over 32 neighbor rows (layer 1, D=128) + ReLU.
// Wave = 1 node x 32 h2-cols x 2 neighbor-halves; 2 D-slices via blockIdx.y.
__global__ __launch_bounds__(256) void median_relu1(
    const _Float16* __restrict__ H, const int* __restrict__ nb,
    _Float16* __restrict__ O) {
  const int lane = threadIdx.x & 63;
  const int h    = lane >> 5;                         // neighbor half
  const int node = blockIdx.x * 4 + (threadIdx.x >> 6);
  const int col2 = blockIdx.y * 32 + (lane & 31);     // h2 column 0..63
  const unsigned coff = (unsigned)col2 * 4u;          // byte offset in row
  const int4* nrow = (const int4*)(nb + (size_t)node * KNB + h * 16);
  const char* Hb = (const char*)H;
  h2 v[16];
  #pragma unroll
  for (int q = 0; q < 4; ++q) {
    const int4 ii = nrow[q];
    v[q * 4 + 0] = *(const h2*)(Hb + (((unsigned)ii.x << 8) + coff));
    v[q * 4 + 1] = *(const h2*)(Hb + (((unsigned)ii.y << 8) + coff));
    v[q * 4 + 2] = *(const h2*)(Hb + (((unsigned)ii.z << 8) + coff));
    v[q * 4 + 3] = *(const h2*)(Hb + (((unsigned)ii.w << 8) + coff));
  }
  const h2 med = median32_pair(v, h);
  if (h == 0) {
    const h2 z = (h2)((_Float16)0);
    *(h2*)((char*)O + ((size_t)node * 256 + coff)) =
        __builtin_elementwise_max(med, z);
  }
}

// Median over 32 neighbor rows (layer 2, D=64); fp32 output.
// Wave = 1 node x 32 h2-cols x 2 neighbor-halves.
__global__ __launch_bounds__(256) void median2(
    const _Float16* __restrict__ H, const int* __restrict__ nb,
    float2* __restrict__ O) {
  const int lane = threadIdx.x & 63;
  const int h    = lane >> 5;
  const int node = blockIdx.x * 4 + (threadIdx.x >> 6);
  const int col2 = lane & 31;                         // h2 column 0..31
  const unsigned coff = (unsigned)col2 * 4u;          // byte offset in row
  const int4* nrow = (const int4*)(nb + (size_t)node * KNB + h * 16);
  const char* Hb = (const char*)H;
  h2 v[16];
  #pragma unroll
  for (int q = 0; q < 4; ++q) {
    const int4 ii = nrow[q];
    v[q * 4 + 0] = *(const h2*)(Hb + (((unsigned)ii.x << 7) + coff));
    v[q * 4 + 1] = *(const h2*)(Hb + (((unsigned)ii.y << 7) + coff));
    v[q * 4 + 2] = *(const h2*)(Hb + (((unsigned)ii.z << 7) + coff));
    v[q * 4 + 3] = *(const h2*)(Hb + (((unsigned)ii.w << 7) + coff));
  }
  const h2 med = median32_pair(v, h);
  if (h == 0) {
    float2 o;
    o.x = (float)med[0];
    o.y = (float)med[1];
    O[(size_t)node * 32 + col2] = o;
  }
}

extern "C" void kernel_launch(void* const* d_in, const int* in_sizes, int n_in,
                              void* d_out, int out_size, void* d_ws, size_t ws_size,
                              hipStream_t stream) {
  const float* feat = (const float*)d_in[0];   // [50000,512]
  const float* W1   = (const float*)d_in[1];   // [512,128]
  const float* b1   = (const float*)d_in[2];   // [128]
  const float* W2   = (const float*)d_in[3];   // [128,64]
  const float* b2   = (const float*)d_in[4];   // [64]
  const int*   nb   = (const int*)d_in[5];     // [50000,32]
  float* out = (float*)d_out;                  // [50000,64] fp32

  _Float16* h1   = (_Float16*)d_ws;                 // 12.8 MB
  _Float16* med1 = h1 + (size_t)NN * 128;           // 12.8 MB
  _Float16* w1t  = med1 + (size_t)NN * 128;         // 128 KB  [128][512]
  _Float16* w2t  = w1t + 128 * 512;                 // 16 KB   [64][128]
  _Float16* h2b  = h1;                              // reuse (h1 dead)

  prep<<<dim3(288), dim3(256), 0, stream>>>(W1, W2, w1t, w2t);
  gemm1_mfma<<<dim3((NN + 63) / 64), dim3(256), 0, stream>>>(feat, w1t, b1, h1, NN);
  median_relu1<<<dim3(NN / 4, 2), dim3(256), 0, stream>>>(h1, nb, med1);
  gemm2_mfma<<<dim3((NN + 63) / 64), dim3(256), 0, stream>>>(med1, w2t, b2, h2b, NN);
  median2<<<dim3(NN / 4), dim3(256), 0, stream>>>(h2b, nb, (float2*)out);
}

// Round 9
// 241.832 us; speedup vs baseline: 2.6331x; 2.6331x over previous
//
#include <hip/hip_runtime.h>
#include <cstddef>

#define NN   50000
#define KNB  32

typedef _Float16 h2    __attribute__((ext_vector_type(2)));
typedef _Float16 h4    __attribute__((ext_vector_type(4)));
typedef _Float16 half8 __attribute__((ext_vector_type(8)));
typedef float    f4    __attribute__((ext_vector_type(4)));

// ---------------- prep: W1^T and W2^T as fp16 [N][K] ----------------------
__global__ __launch_bounds__(256) void prep(const float* __restrict__ W1,
                                            const float* __restrict__ W2,
                                            _Float16* __restrict__ w1t,
                                            _Float16* __restrict__ w2t) {
  const int id = blockIdx.x * 256 + threadIdx.x;
  if (id < 128 * 512) {                     // w1t[n][k] = W1[k][n]
    const int n = id >> 9, k = id & 511;
    w1t[id] = (_Float16)W1[k * 128 + n];
  } else {
    const int id2 = id - 128 * 512;
    if (id2 < 64 * 128) {                   // w2t[n][k] = W2[k][n]
      const int n = id2 >> 7, k = id2 & 127;
      w2t[id2] = (_Float16)W2[k * 64 + n];
    }
  }
}

// ---------------- GEMM1: H1[M,128] = A[M,512]fp32 @ W1 + b1, fp16 out -----
// R11 structure (lane-consecutive staging, BM=64, BK=64). ~7.7us warm
// (R14 REPS=8 delta) -- near floor. Unchanged.
__global__ __launch_bounds__(256) void gemm1_mfma(
    const float* __restrict__ A, const _Float16* __restrict__ Bt,
    const float* __restrict__ bias, _Float16* __restrict__ C, int M) {
  constexpr int K = 512, BM = 64, BK = 64;
  __shared__ _Float16 Ah[BM][72];     // 9 KB, 144B stride
  __shared__ _Float16 Bh[128][72];    // 18 KB
  const int tid  = threadIdx.x;
  const int wave = tid >> 6;
  const int lane = tid & 63;
  const int mr   = lane & 15;
  const int kg   = lane >> 4;
  const int m0   = blockIdx.x * BM;

  const int ar = tid >> 4;            // 0..15 (+ c*16)
  const int ac = (tid & 15) * 4;      // fp32 col within BK
  const int br = tid >> 3;            // 0..31 (+ c*32)
  const int bc = (tid & 7) * 8;       // fp16 col within BK

  f4 acc[8] = {};

  for (int k0 = 0; k0 < K; k0 += BK) {
    #pragma unroll
    for (int c = 0; c < 4; ++c) {
      const int arow = c * 16 + ar;
      int aRow = m0 + arow;
      if (aRow >= M) aRow = M - 1;    // clamp; garbage rows dropped at store
      const f4 t = *(const f4*)(A + (size_t)aRow * K + k0 + ac);
      h4 hv = {(_Float16)t[0], (_Float16)t[1], (_Float16)t[2], (_Float16)t[3]};
      *(h4*)&Ah[arow][ac] = hv;
      const int brow = c * 32 + br;
      *(half8*)&Bh[brow][bc] =
          *(const half8*)(Bt + (size_t)brow * K + k0 + bc);
    }
    __syncthreads();

    #pragma unroll
    for (int kk = 0; kk < 2; ++kk) {
      const half8 af = *(const half8*)&Ah[wave * 16 + mr][kk * 32 + kg * 8];
      #pragma unroll
      for (int nt = 0; nt < 8; ++nt) {
        const half8 bf = *(const half8*)&Bh[nt * 16 + mr][kk * 32 + kg * 8];
        acc[nt] = __builtin_amdgcn_mfma_f32_16x16x32_f16(af, bf, acc[nt], 0, 0, 0);
      }
    }
    __syncthreads();
  }

  #pragma unroll
  for (int nt = 0; nt < 8; ++nt) {
    const int col = nt * 16 + mr;
    const float bv = bias[col];
    #pragma unroll
    for (int r = 0; r < 4; ++r) {
      const int row = m0 + wave * 16 + kg * 4 + r;
      if (row < M)
        C[(size_t)row * 128 + col] = (_Float16)(acc[nt][r] + bv);
    }
  }
}

// ---------------- GEMM2: H2[M,64] = A[M,128]fp16 @ W2 + b2, fp16 out ------
// R11 structure. Unchanged.
__global__ __launch_bounds__(256) void gemm2_mfma(
    const _Float16* __restrict__ A, const _Float16* __restrict__ Bt,
    const float* __restrict__ bias, _Float16* __restrict__ C, int M) {
  constexpr int K = 128, BM = 64, BK = 64;
  __shared__ _Float16 Ah[BM][72];     // 9 KB
  __shared__ _Float16 Bh[64][72];     // 9 KB
  const int tid  = threadIdx.x;
  const int wave = tid >> 6;
  const int lane = tid & 63;
  const int mr   = lane & 15;
  const int kg   = lane >> 4;
  const int m0   = blockIdx.x * BM;

  const int sr = tid >> 3;            // 0..31 (+ c*32)
  const int sc = (tid & 7) * 8;

  f4 acc[4] = {};

  #pragma unroll
  for (int k0 = 0; k0 < K; k0 += BK) {
    #pragma unroll
    for (int c = 0; c < 2; ++c) {
      const int srow = c * 32 + sr;
      int aRow = m0 + srow;
      if (aRow >= M) aRow = M - 1;
      *(half8*)&Ah[srow][sc] = *(const half8*)(A + (size_t)aRow * K + k0 + sc);
      *(half8*)&Bh[srow][sc] = *(const half8*)(Bt + (size_t)srow * K + k0 + sc);
    }
    __syncthreads();

    #pragma unroll
    for (int kk = 0; kk < 2; ++kk) {
      const half8 af = *(const half8*)&Ah[wave * 16 + mr][kk * 32 + kg * 8];
      #pragma unroll
      for (int nt = 0; nt < 4; ++nt) {
        const half8 bf = *(const half8*)&Bh[nt * 16 + mr][kk * 32 + kg * 8];
        acc[nt] = __builtin_amdgcn_mfma_f32_16x16x32_f16(af, bf, acc[nt], 0, 0, 0);
      }
    }
    __syncthreads();
  }

  #pragma unroll
  for (int nt = 0; nt < 4; ++nt) {
    const int col = nt * 16 + mr;
    const float bv = bias[col];
    #pragma unroll
    for (int r = 0; r < 4; ++r) {
      const int row = m0 + wave * 16 + kg * 4 + r;
      if (row < M)
        C[(size_t)row * 64 + col] = (_Float16)(acc[nt][r] + bv);
    }
  }
}

// ---------------- median machinery ----------------------------------------
// R17: sort-park-sort-merge with EXPLICIT AGPR parking. R14 proved the
// compiler parks the 32-live array in AGPRs and bounces per comparator
// (~450 accvgpr copies, 2.3x VALU). R16's shfl merge regressed 9x (serial
// ds_bpermute chain -- reverted). Here: sort half A (16 live VGPRs), park
// sorted A in AGPRs (16 explicit v_accvgpr_write), sort half B (16 live),
// stream A back during the merge fold (16 reads). 32 copies total, peak
// unified liveness ~45 regs < 64 -> full occupancy, no allocator bouncing.
// Value network identical to R9 -> bit-identical output.
__device__ __forceinline__ void ceh(h2& a, h2& b) {
  h2 lo = __builtin_elementwise_min(a, b);
  h2 hi = __builtin_elementwise_max(a, b);
  a = lo;
  b = hi;
}

// Batcher odd-even mergesort over a 16-array (63 comparators).
__device__ __forceinline__ void sort16h(h2 (&v)[16]) {
  #pragma unroll
  for (int p = 1; p < 16; p <<= 1) {
    #pragma unroll
    for (int k = p; k >= 1; k >>= 1) {
      #pragma unroll
      for (int j = k & (p - 1); j + k < 16; j += 2 * k) {
        #pragma unroll
        for (int i = 0; i < k; ++i) {
          if (i + j + k < 16) {
            if ((i + j) / (2 * p) == (i + j + k) / (2 * p)) {
              ceh(v[i + j], v[i + j + k]);
            }
          }
        }
      }
    }
  }
}

__device__ __forceinline__ int agpr_park(h2 x) {
  int r;
  asm("v_accvgpr_write_b32 %0, %1"
      : "=a"(r) : "v"(__builtin_bit_cast(int, x)));
  return r;
}
__device__ __forceinline__ h2 agpr_get(int x) {
  int r;
  asm("v_accvgpr_read_b32 %0, %1" : "=v"(r) : "a"(x));
  return __builtin_bit_cast(h2, r);
}

template <int SHIFT>
__device__ __forceinline__ h2 median32_park(const int4* nrow,
                                            const char* Hb, unsigned coff) {
  h2 a[16];
  #pragma unroll
  for (int q = 0; q < 4; ++q) {
    const int4 ii = nrow[q];
    a[q * 4 + 0] = *(const h2*)(Hb + (((unsigned)ii.x << SHIFT) + coff));
    a[q * 4 + 1] = *(const h2*)(Hb + (((unsigned)ii.y << SHIFT) + coff));
    a[q * 4 + 2] = *(const h2*)(Hb + (((unsigned)ii.z << SHIFT) + coff));
    a[q * 4 + 3] = *(const h2*)(Hb + (((unsigned)ii.w << SHIFT) + coff));
  }
  sort16h(a);
  int ap[16];
  #pragma unroll
  for (int i = 0; i < 16; ++i) ap[i] = agpr_park(a[i]);

  h2 b[16];
  #pragma unroll
  for (int q = 0; q < 4; ++q) {
    const int4 ii = nrow[4 + q];
    b[q * 4 + 0] = *(const h2*)(Hb + (((unsigned)ii.x << SHIFT) + coff));
    b[q * 4 + 1] = *(const h2*)(Hb + (((unsigned)ii.y << SHIFT) + coff));
    b[q * 4 + 2] = *(const h2*)(Hb + (((unsigned)ii.z << SHIFT) + coff));
    b[q * 4 + 3] = *(const h2*)(Hb + (((unsigned)ii.w << SHIFT) + coff));
  }
  sort16h(b);

  // med = min(a[15], b[15], max(a[i], b[14-i]) for i=0..14)   [R9-verified]
  h2 m = __builtin_elementwise_min(agpr_get(ap[15]), b[15]);
  #pragma unroll
  for (int i = 0; i < 15; ++i) {
    m = __builtin_elementwise_min(
        m, __builtin_elementwise_max(agpr_get(ap[i]), b[14 - i]));
  }
  return m;
}

// Median over 32 neighbor rows (layer 1, D=128) + ReLU.
// Wave = 2 nodes x 32 lanes; 2 D-slices via blockIdx.y. Row = 256 B.
__global__ __launch_bounds__(256, 4) void median_relu1(
    const _Float16* __restrict__ H, const int* __restrict__ nb,
    _Float16* __restrict__ O) {
  const int lane = threadIdx.x & 63;
  const int node = blockIdx.x * 8 + ((threadIdx.x >> 6) << 1) + (lane >> 5);
  const int col2 = blockIdx.y * 32 + (lane & 31);     // h2 column 0..63
  const unsigned coff = (unsigned)col2 * 4u;          // byte offset in row
  const int4* nrow = (const int4*)(nb + (size_t)node * KNB);
  const h2 med = median32_park<8>(nrow, (const char*)H, coff);
  const h2 z = (h2)((_Float16)0);
  *(h2*)((char*)O + ((size_t)node * 256 + coff)) =
      __builtin_elementwise_max(med, z);
}

// Median over 32 neighbor rows (layer 2, D=64); fp32 output. Row = 128 B.
__global__ __launch_bounds__(256, 4) void median2(
    const _Float16* __restrict__ H, const int* __restrict__ nb,
    float2* __restrict__ O) {
  const int node = blockIdx.x * 8 + (threadIdx.x >> 5);
  const int lane = threadIdx.x & 31;
  const unsigned coff = (unsigned)lane * 4u;          // byte offset in row
  const int4* nrow = (const int4*)(nb + (size_t)node * KNB);
  const h2 med = median32_park<7>(nrow, (const char*)H, coff);
  float2 o;
  o.x = (float)med[0];
  o.y = (float)med[1];
  O[(size_t)node * 32 + lane] = o;
}

extern "C" void kernel_launch(void* const* d_in, const int* in_sizes, int n_in,
                              void* d_out, int out_size, void* d_ws, size_t ws_size,
                              hipStream_t stream) {
  const float* feat = (const float*)d_in[0];   // [50000,512]
  const float* W1   = (const float*)d_in[1];   // [512,128]
  const float* b1   = (const float*)d_in[2];   // [128]
  const float* W2   = (const float*)d_in[3];   // [128,64]
  const float* b2   = (const float*)d_in[4];   // [64]
  const int*   nb   = (const int*)d_in[5];     // [50000,32]
  float* out = (float*)d_out;                  // [50000,64] fp32

  _Float16* h1   = (_Float16*)d_ws;                 // 12.8 MB
  _Float16* med1 = h1 + (size_t)NN * 128;           // 12.8 MB
  _Float16* w1t  = med1 + (size_t)NN * 128;         // 128 KB  [128][512]
  _Float16* w2t  = w1t + 128 * 512;                 // 16 KB   [64][128]
  _Float16* h2b  = h1;                              // reuse (h1 dead)

  prep<<<dim3(288), dim3(256), 0, stream>>>(W1, W2, w1t, w2t);
  gemm1_mfma<<<dim3((NN + 63) / 64), dim3(256), 0, stream>>>(feat, w1t, b1, h1, NN);
  median_relu1<<<dim3(NN / 8, 2), dim3(256), 0, stream>>>(h1, nb, med1);
  gemm2_mfma<<<dim3((NN + 63) / 64), dim3(256), 0, stream>>>(med1, w2t, b2, h2b, NN);
  median2<<<dim3(NN / 8), dim3(256), 0, stream>>>(h2b, nb, (float2*)out);
}